// Round 8
// baseline (110.418 us; speedup 1.0000x reference)
//
#include <hip/hip_runtime.h>
#include <hip/hip_bf16.h>
#include <math.h>

// Problem constants (DeepFM)
#define BTOT   16384
#define NF     26
#define VOCAB  100000
#define EDIM   16
#define DD     13
#define KPAD   448      // 429 padded to 14*32
#define KREAL  429
#define N1     256
#define N2     128
#define SPB    32       // samples per block
#define APAD   456      // A tile row stride (448+8)
#define H2PAD  264      // H2 tile row stride (256+8)
#define NCONV  384      // blocks participating in weight conversion
#define MAGIC  0x13572468

typedef __attribute__((ext_vector_type(8))) short bf16x8;
typedef __attribute__((ext_vector_type(4))) short bf16x4;
typedef __attribute__((ext_vector_type(4))) float f32x4;

static __device__ __forceinline__ bf16x8 ldb8(const __hip_bfloat16* p) {
  return *reinterpret_cast<const bf16x8*>(p);
}
static __device__ __forceinline__ short f2bf(float f) {
  __hip_bfloat16 h = __float2bfloat16(f);
  return *reinterpret_cast<short*>(&h);
}

// ---------------------------------------------------------------------------
// Single fused kernel. 512 thr = 8 waves, SPB=32, grid 512 = 2 blocks/CU
// (co-resident: __launch_bounds__(512,4) caps VGPR so 16 waves/CU fit).
//
// Phase 0 (blocks 0..383): repack W1/W2 -> bf16 B-fragment layout in ws
//   (identical work split to the old standalone convert kernel), then
//   device-scope release-store flag[bid]=MAGIC.
//   Replays: flags stay MAGIC and W1f is re-written with identical bytes,
//   so skipping the wait is deterministic.
// Phase 1 (all blocks): embedding gather -> LDS A tile + FM linear/cross.
//   Runs before the wait, hiding conversion latency.
// Wait: threads 0..383 acquire-load their flag until MAGIC.
// Phase 2: GEMM1 (A[32,448] x W1f^T) +b1, ReLU -> LDS H2 tile.
// Phase 3: GEMM2 (H2[32,256] x W2f^T) +b2, ReLU, dot Wout.
// Phase 4: + fm logit, sigmoid -> out.
// ---------------------------------------------------------------------------
__global__ __launch_bounds__(512, 4) void deepfm_fused(
    const int* __restrict__ Xs, const float* __restrict__ Xd,
    const float* __restrict__ linW, const float* __restrict__ fmW,
    const float* __restrict__ denseW, const float* __restrict__ denseB,
    const float* __restrict__ W1, const float* __restrict__ b1,
    const float* __restrict__ W2, const float* __restrict__ b2,
    const float* __restrict__ Wout, float* __restrict__ out,
    __hip_bfloat16* __restrict__ W1f, __hip_bfloat16* __restrict__ W2f,
    int* __restrict__ flags) {

  __shared__ __hip_bfloat16 Ash[SPB][APAD];
  __shared__ __hip_bfloat16 H2sh[SPB][H2PAD];
  __shared__ float fmlsh[SPB];
  __shared__ float redsh[SPB][8];

  const int tid = threadIdx.x;
  const int bid = blockIdx.x;
  const size_t blk0 = (size_t)bid * SPB;

  // ---------------- phase 0: weight conversion (blocks 0..383) ------------
  if (bid < NCONV) {
    const int k = tid;
    if (bid < 256) {
      const int n = bid;
      if (k < 448) {
        float v = (k < KREAL) ? W1[(size_t)n * KREAL + k] : 0.f;
        W1f[(((size_t)(k >> 3)) * N1 + n) * 8 + (k & 7)] = __float2bfloat16(v);
      }
    } else {
      const int n = bid - 256;
      if (k < 256) {
        float v = W2[(size_t)n * 256 + k];
        W2f[(((size_t)(k >> 3)) * N2 + n) * 8 + (k & 7)] = __float2bfloat16(v);
      }
    }
    // publish: make stores visible device-wide, then set this block's flag
    __syncthreads();
    __threadfence();
    if (tid == 0)
      __hip_atomic_store(&flags[bid], MAGIC, __ATOMIC_RELEASE,
                         __HIP_MEMORY_SCOPE_AGENT);
  }

  // ---------------- phase 1: gather + FM ----------------
  {
    const int s   = tid >> 4;     // local sample 0..31
    const int sub = tid & 15;
    const int q   = sub & 3;      // e-quarter: dims q*4..q*4+3
    const int g   = sub >> 2;     // field group: fields g+4i
    const size_t b = blk0 + s;
    const int* xrow = Xs + b * NF;

    int idxs[7];
#pragma unroll
    for (int i = 0; i < 7; ++i) {
      int f = g + 4 * i;
      idxs[i] = (f < NF) ? xrow[f] : 0;
    }

    f32x4 sum = (f32x4){0.f, 0.f, 0.f, 0.f};
    f32x4 sumsq = (f32x4){0.f, 0.f, 0.f, 0.f};
    float part = 0.f;

#pragma unroll
    for (int i = 0; i < 7; ++i) {
      const int f = g + 4 * i;
      if (f < NF) {
        const float* row = fmW + ((size_t)f * VOCAB + idxs[i]) * EDIM;
        f32x4 v = *reinterpret_cast<const f32x4*>(row + q * 4);
        sum += v;
        sumsq += v * v;
        bf16x4 pk;
        pk[0] = f2bf(v[0]); pk[1] = f2bf(v[1]);
        pk[2] = f2bf(v[2]); pk[3] = f2bf(v[3]);
        *reinterpret_cast<bf16x4*>(&Ash[s][f * EDIM + q * 4]) = pk;
        if (q == (i & 3))
          part += linW[(size_t)f * VOCAB + idxs[i]];
      }
    }
#pragma unroll
    for (int off = 4; off <= 8; off <<= 1) {
#pragma unroll
      for (int c = 0; c < 4; ++c) {
        sum[c] += __shfl_xor(sum[c], off);
        sumsq[c] += __shfl_xor(sumsq[c], off);
      }
    }
    if (g == 0) {
      f32x4 c4 = sum * sum - sumsq;
      part += 0.5f * (c4[0] + c4[1] + c4[2] + c4[3]);
    }
    float xd = (sub < DD) ? Xd[b * DD + sub] : 0.f;
    Ash[s][416 + sub] = __float2bfloat16(xd);
    Ash[s][432 + sub] = __float2bfloat16(0.f);
    if (sub < DD) part += xd * denseW[sub];
#pragma unroll
    for (int off = 1; off < 16; off <<= 1)
      part += __shfl_xor(part, off);
    if (sub == 0) fmlsh[s] = part + denseB[0];
  }

  // ---------------- wait for weight conversion ----------------------------
  if (tid < NCONV) {
    while (__hip_atomic_load(&flags[tid], __ATOMIC_ACQUIRE,
                             __HIP_MEMORY_SCOPE_AGENT) != MAGIC)
      __builtin_amdgcn_s_sleep(8);
  }
  __syncthreads();

  // ---------------- phase 2: GEMM1 -> H2sh ----------------
  const int wave = tid >> 6;      // 0..7
  const int lane = tid & 63;
  const int lr = lane & 15;
  const int kg = lane >> 4;
  {
    const int n0 = wave * 32;
    f32x4 acc[2][2];
#pragma unroll
    for (int mt = 0; mt < 2; ++mt)
#pragma unroll
      for (int nt = 0; nt < 2; ++nt) acc[mt][nt] = (f32x4){0.f, 0.f, 0.f, 0.f};

#pragma unroll
    for (int kt = 0; kt < KPAD / 32; ++kt) {
      const int kbase = kt * 32 + kg * 8;
      bf16x8 af[2];
#pragma unroll
      for (int mt = 0; mt < 2; ++mt)
        af[mt] = *reinterpret_cast<const bf16x8*>(&Ash[mt * 16 + lr][kbase]);
#pragma unroll
      for (int nt = 0; nt < 2; ++nt) {
        bf16x8 bf = ldb8(W1f + ((size_t)(kbase >> 3) * N1 + n0 + nt * 16 + lr) * 8);
        acc[0][nt] = __builtin_amdgcn_mfma_f32_16x16x32_bf16(af[0], bf, acc[0][nt], 0, 0, 0);
        acc[1][nt] = __builtin_amdgcn_mfma_f32_16x16x32_bf16(af[1], bf, acc[1][nt], 0, 0, 0);
      }
    }
#pragma unroll
    for (int nt = 0; nt < 2; ++nt) {
      const int col = n0 + nt * 16 + lr;
      const float bias = b1[col];
#pragma unroll
      for (int mt = 0; mt < 2; ++mt) {
#pragma unroll
        for (int r = 0; r < 4; ++r) {
          float v = acc[mt][nt][r] + bias;
          v = v > 0.f ? v : 0.f;
          H2sh[mt * 16 + kg * 4 + r][col] = __float2bfloat16(v);
        }
      }
    }
  }
  __syncthreads();

  // ---------------- phase 3: GEMM2 + Wout dot ----------------
  {
    const int n0 = wave * 16;     // 8 waves x 16 = 128 cols
    f32x4 acc[2];
    acc[0] = (f32x4){0.f, 0.f, 0.f, 0.f};
    acc[1] = (f32x4){0.f, 0.f, 0.f, 0.f};

#pragma unroll
    for (int kt = 0; kt < N1 / 32; ++kt) {
      const int kbase = kt * 32 + kg * 8;
      bf16x8 bf = ldb8(W2f + ((size_t)(kbase >> 3) * N2 + n0 + lr) * 8);
#pragma unroll
      for (int mt = 0; mt < 2; ++mt) {
        bf16x8 af = *reinterpret_cast<const bf16x8*>(&H2sh[mt * 16 + lr][kbase]);
        acc[mt] = __builtin_amdgcn_mfma_f32_16x16x32_bf16(af, bf, acc[mt], 0, 0, 0);
      }
    }
    const float w0 = Wout[n0 + lr];
    const float bb0 = b2[n0 + lr];
#pragma unroll
    for (int mt = 0; mt < 2; ++mt) {
#pragma unroll
      for (int r = 0; r < 4; ++r) {
        float v = acc[mt][r] + bb0;
        v = v > 0.f ? v : 0.f;
        v *= w0;
#pragma unroll
        for (int off = 1; off < 16; off <<= 1)
          v += __shfl_xor(v, off);
        if (lr == 0) redsh[mt * 16 + kg * 4 + r][wave] = v;
      }
    }
  }
  __syncthreads();

  // ---------------- phase 4: combine + sigmoid ----------------
  if (tid < SPB) {
    const int row = tid;
    float t = 0.f;
#pragma unroll
    for (int w = 0; w < 8; ++w) t += redsh[row][w];
    float x = fmlsh[row] + t;
    out[blk0 + row] = 1.f / (1.f + expf(-x));
  }
}

// ---------------------------------------------------------------------------
extern "C" void kernel_launch(void* const* d_in, const int* in_sizes, int n_in,
                              void* d_out, int out_size, void* d_ws, size_t ws_size,
                              hipStream_t stream) {
  const int*   Xs   = (const int*)d_in[0];
  const float* Xd   = (const float*)d_in[1];
  const float* linW = (const float*)d_in[2];
  const float* fmW  = (const float*)d_in[3];
  const float* dW   = (const float*)d_in[4];
  const float* dB   = (const float*)d_in[5];
  const float* W1   = (const float*)d_in[6];
  const float* b1   = (const float*)d_in[7];
  const float* W2   = (const float*)d_in[8];
  const float* b2   = (const float*)d_in[9];
  const float* Wout = (const float*)d_in[10];
  float* out = (float*)d_out;

  char* ws = (char*)d_ws;
  __hip_bfloat16* W1f = (__hip_bfloat16*)(ws);             // 448*256*2 = 229,376
  __hip_bfloat16* W2f = (__hip_bfloat16*)(ws + 229376);    // 256*128*2 =  65,536
  int*            flg = (int*)(ws + 294912);               // 384*4     =   1,536

  deepfm_fused<<<BTOT / SPB, 512, 0, stream>>>(
      Xs, Xd, linW, fmW, dW, dB, W1, b1, W2, b2, Wout, out, W1f, W2f, flg);
}

// Round 9
// 33.914 us; speedup vs baseline: 3.2559x; 3.2559x over previous
//
#include <hip/hip_runtime.h>
#include <hip/hip_bf16.h>
#include <math.h>

// Problem constants (DeepFM)
#define BTOT   16384
#define NF     26
#define VOCAB  100000
#define EDIM   16
#define DD     13
#define KPAD   448      // 429 padded to 14*32
#define KREAL  429
#define N1     256
#define N2     128
#define SPB    64       // samples per GEMM block
#define APAD   456      // A tile row stride in LDS (448+8)
#define H2PAD  264      // H2 tile row stride (256+8)

typedef __attribute__((ext_vector_type(8))) short bf16x8;
typedef __attribute__((ext_vector_type(4))) short bf16x4;
typedef __attribute__((ext_vector_type(4))) float f32x4;

static __device__ __forceinline__ bf16x8 ldb8(const __hip_bfloat16* p) {
  return *reinterpret_cast<const bf16x8*>(p);
}
static __device__ __forceinline__ short f2bf(float f) {
  __hip_bfloat16 h = __float2bfloat16(f);
  return *reinterpret_cast<short*>(&h);
}

// ---------------------------------------------------------------------------
// Kernel A: gather + FM (+ weight conversion folded into blocks 0..383).
// 256 thr = 4 waves, 16 samples/block, grid 1024; __launch_bounds__(256,8)
// targets VGPR<=64 -> 8 waves/SIMD = 32 waves/CU for max memory-level
// parallelism on the latency-bound random gathers.
// Writes: A [B][448] bf16 rows (DNN input), fml [B] f32 (FM logit part),
//         W1f/W2f packed bf16 B-fragment layouts (blocks 0..383).
// No cross-block dependency: consumers are in kernel B.
// ---------------------------------------------------------------------------
__global__ __launch_bounds__(256, 8) void gather_conv(
    const int* __restrict__ Xs, const float* __restrict__ Xd,
    const float* __restrict__ linW, const float* __restrict__ fmW,
    const float* __restrict__ denseW, const float* __restrict__ denseB,
    const float* __restrict__ W1, const float* __restrict__ W2,
    __hip_bfloat16* __restrict__ Aout, float* __restrict__ fml,
    __hip_bfloat16* __restrict__ W1f, __hip_bfloat16* __restrict__ W2f) {
  const int tid = threadIdx.x;
  const int bid = blockIdx.x;

  // ---- folded weight conversion (blocks 0..383) ----
  if (bid < 256) {                    // W1: row n = bid, k strided by 256
    const int n = bid;
    for (int kk = tid; kk < KPAD; kk += 256) {
      float v = (kk < KREAL) ? W1[(size_t)n * KREAL + kk] : 0.f;
      W1f[(((size_t)(kk >> 3)) * N1 + n) * 8 + (kk & 7)] = __float2bfloat16(v);
    }
  } else if (bid < 384) {             // W2: row n = bid-256, k = tid
    const int n = bid - 256;
    float v = W2[(size_t)n * N1 + tid];
    W2f[(((size_t)(tid >> 3)) * N2 + n) * 8 + (tid & 7)] = __float2bfloat16(v);
  }

  // ---- gather + FM ----
  const int s   = tid >> 4;           // local sample 0..15
  const int sub = tid & 15;
  const int q   = sub & 3;            // e-quarter
  const int g   = sub >> 2;           // field group: fields g+4i
  const size_t b = (size_t)bid * 16 + s;
  const int* xrow = Xs + b * NF;

  int idxs[7];
#pragma unroll
  for (int i = 0; i < 7; ++i) {
    int f = g + 4 * i;
    idxs[i] = (f < NF) ? xrow[f] : 0;
  }

  f32x4 sum = (f32x4){0.f, 0.f, 0.f, 0.f};
  f32x4 sumsq = (f32x4){0.f, 0.f, 0.f, 0.f};
  float part = 0.f;
  __hip_bfloat16* arow = Aout + b * KPAD;

#pragma unroll
  for (int i = 0; i < 7; ++i) {
    const int f = g + 4 * i;
    if (f < NF) {
      const float* row = fmW + ((size_t)f * VOCAB + idxs[i]) * EDIM;
      f32x4 v = *reinterpret_cast<const f32x4*>(row + q * 4);
      sum += v;
      sumsq += v * v;
      bf16x4 pk;
      pk[0] = f2bf(v[0]); pk[1] = f2bf(v[1]);
      pk[2] = f2bf(v[2]); pk[3] = f2bf(v[3]);
      *reinterpret_cast<bf16x4*>(&arow[f * EDIM + q * 4]) = pk;
      if (q == (i & 3))               // each field's lin value counted once
        part += linW[(size_t)f * VOCAB + idxs[i]];
    }
  }
  // reduce sum/sumsq over field-groups (lanes xor 4, 8)
#pragma unroll
  for (int off = 4; off <= 8; off <<= 1) {
#pragma unroll
    for (int c = 0; c < 4; ++c) {
      sum[c] += __shfl_xor(sum[c], off);
      sumsq[c] += __shfl_xor(sumsq[c], off);
    }
  }
  if (g == 0) {                       // each e-quarter's cross counted once
    f32x4 c4 = sum * sum - sumsq;
    part += 0.5f * (c4[0] + c4[1] + c4[2] + c4[3]);
  }
  // dense features + zero pad
  float xd = (sub < DD) ? Xd[b * DD + sub] : 0.f;
  arow[416 + sub] = __float2bfloat16(xd);
  arow[432 + sub] = __float2bfloat16(0.f);
  if (sub < DD) part += xd * denseW[sub];
  // reduce over 16-lane sample group
#pragma unroll
  for (int off = 1; off < 16; off <<= 1)
    part += __shfl_xor(part, off);
  if (sub == 0) fml[b] = part + denseB[0];
}

// ---------------------------------------------------------------------------
// Kernel B: A-stage + GEMM1 + GEMM2 + sigmoid. 1024 thr = 16 waves,
// 64 samples/block, grid 256 (R4's proven shape).
// ---------------------------------------------------------------------------
__global__ __launch_bounds__(1024, 4) void gemm_fused(
    const __hip_bfloat16* __restrict__ Aout, const float* __restrict__ fml,
    const __hip_bfloat16* __restrict__ W1f, const float* __restrict__ b1,
    const __hip_bfloat16* __restrict__ W2f, const float* __restrict__ b2,
    const float* __restrict__ Wout, float* __restrict__ out) {

  __shared__ __hip_bfloat16 Ash[SPB][APAD];
  __shared__ __hip_bfloat16 H2sh[SPB][H2PAD];
  __shared__ float redsh[SPB][8];

  const int tid = threadIdx.x;
  const size_t blk0 = (size_t)blockIdx.x * SPB;

  // ---------------- stage A tile (coalesced 16B loads) ----------------
  {
    // 64 rows x 56 bf16x8 slots = 3584 slots; 1024 threads x 4 rounds
#pragma unroll
    for (int v = tid; v < SPB * 56; v += 1024) {
      const int row = v / 56;
      const int c8 = v - row * 56;
      bf16x8 x = ldb8(Aout + (blk0 + row) * KPAD + c8 * 8);
      *reinterpret_cast<bf16x8*>(&Ash[row][c8 * 8]) = x;
    }
  }
  __syncthreads();

  // ---------------- GEMM1 -> H2sh ----------------
  const int wave = tid >> 6;      // 0..15
  const int lane = tid & 63;
  const int lr = lane & 15;
  const int kg = lane >> 4;
  {
    const int n0 = wave * 16;     // 16 waves x 16 cols = 256
    f32x4 acc[4];
#pragma unroll
    for (int mt = 0; mt < 4; ++mt) acc[mt] = (f32x4){0.f, 0.f, 0.f, 0.f};

#pragma unroll
    for (int kt = 0; kt < KPAD / 32; ++kt) {
      const int kbase = kt * 32 + kg * 8;
      bf16x8 bf = ldb8(W1f + ((size_t)(kbase >> 3) * N1 + n0 + lr) * 8);
#pragma unroll
      for (int mt = 0; mt < 4; ++mt) {
        bf16x8 af = *reinterpret_cast<const bf16x8*>(&Ash[mt * 16 + lr][kbase]);
        acc[mt] = __builtin_amdgcn_mfma_f32_16x16x32_bf16(af, bf, acc[mt], 0, 0, 0);
      }
    }
    const int col = n0 + lr;
    const float bias = b1[col];
#pragma unroll
    for (int mt = 0; mt < 4; ++mt) {
#pragma unroll
      for (int r = 0; r < 4; ++r) {
        float v = acc[mt][r] + bias;
        v = v > 0.f ? v : 0.f;
        H2sh[mt * 16 + kg * 4 + r][col] = __float2bfloat16(v);
      }
    }
  }
  __syncthreads();

  // ---------------- GEMM2 + Wout dot ----------------
  {
    const int c  = wave & 7;      // col-slice (16 cols)
    const int h  = wave >> 3;     // m-half (32 rows)
    const int n0 = c * 16;
    f32x4 acc[2];
    acc[0] = (f32x4){0.f, 0.f, 0.f, 0.f};
    acc[1] = (f32x4){0.f, 0.f, 0.f, 0.f};

#pragma unroll
    for (int kt = 0; kt < N1 / 32; ++kt) {
      const int kbase = kt * 32 + kg * 8;
      bf16x8 bf = ldb8(W2f + ((size_t)(kbase >> 3) * N2 + n0 + lr) * 8);
#pragma unroll
      for (int mt = 0; mt < 2; ++mt) {
        bf16x8 af = *reinterpret_cast<const bf16x8*>(&H2sh[h * 32 + mt * 16 + lr][kbase]);
        acc[mt] = __builtin_amdgcn_mfma_f32_16x16x32_bf16(af, bf, acc[mt], 0, 0, 0);
      }
    }
    const float w0 = Wout[n0 + lr];
    const float bb0 = b2[n0 + lr];
#pragma unroll
    for (int mt = 0; mt < 2; ++mt) {
#pragma unroll
      for (int r = 0; r < 4; ++r) {
        float v = acc[mt][r] + bb0;
        v = v > 0.f ? v : 0.f;
        v *= w0;
#pragma unroll
        for (int off = 1; off < 16; off <<= 1)
          v += __shfl_xor(v, off);
        if (lr == 0) redsh[h * 32 + mt * 16 + kg * 4 + r][c] = v;
      }
    }
  }
  __syncthreads();

  // ---------------- combine + sigmoid ----------------
  if (tid < SPB) {
    const int row = tid;
    float t = 0.f;
#pragma unroll
    for (int w = 0; w < 8; ++w) t += redsh[row][w];
    float x = fml[blk0 + row] + t;
    out[blk0 + row] = 1.f / (1.f + expf(-x));
  }
}

// ---------------------------------------------------------------------------
extern "C" void kernel_launch(void* const* d_in, const int* in_sizes, int n_in,
                              void* d_out, int out_size, void* d_ws, size_t ws_size,
                              hipStream_t stream) {
  const int*   Xs   = (const int*)d_in[0];
  const float* Xd   = (const float*)d_in[1];
  const float* linW = (const float*)d_in[2];
  const float* fmW  = (const float*)d_in[3];
  const float* dW   = (const float*)d_in[4];
  const float* dB   = (const float*)d_in[5];
  const float* W1   = (const float*)d_in[6];
  const float* b1   = (const float*)d_in[7];
  const float* W2   = (const float*)d_in[8];
  const float* b2   = (const float*)d_in[9];
  const float* Wout = (const float*)d_in[10];
  float* out = (float*)d_out;

  char* ws = (char*)d_ws;
  __hip_bfloat16* A   = (__hip_bfloat16*)(ws);             // B*448*2   = 14,680,064
  float*          fml = (float*)(ws + 14680064);           // B*4       =     65,536
  __hip_bfloat16* W1f = (__hip_bfloat16*)(ws + 14745600);  // 448*256*2 =    229,376
  __hip_bfloat16* W2f = (__hip_bfloat16*)(ws + 14974976);  // 256*128*2 =     65,536

  gather_conv<<<BTOT / 16, 256, 0, stream>>>(
      Xs, Xd, linW, fmW, dW, dB, W1, W2, A, fml, W1f, W2f);
  gemm_fused<<<BTOT / SPB, 1024, 0, stream>>>(
      A, fml, W1f, b1, W2f, b2, Wout, out);
}